// Round 3
// baseline (257.092 us; speedup 1.0000x reference)
//
#include <hip/hip_runtime.h>
#include <stdint.h>

#define NBINS 256
#define HW    (512 * 512)   // pixels per image
#define NIMG  64

// float64 grayscale; weights are the fp32 RGB_W constants widened to double
// (products of fp32 values in double are exact; sum order irrelevant at f64 precision)
__device__ __forceinline__ double gray_of(float r, float g, float b) {
    return fma((double)b, (double)0.1140f,
           fma((double)g, (double)0.5870f,
               (double)r * (double)0.2989f));
}

__global__ void k_init(unsigned long long* __restrict__ minmax, unsigned* __restrict__ hist) {
    const int i = blockIdx.x * blockDim.x + threadIdx.x;
    if (i < NIMG * NBINS) hist[i] = 0u;
    const int j = i - NIMG * NBINS;
    if (j >= 0 && j < NIMG) {
        minmax[j * 2 + 0] = 0x7FF0000000000000ULL;  // +inf
        minmax[j * 2 + 1] = 0ULL;                   // 0.0
    }
}

// 256 blocks per image, 256 threads, 4 pixels/thread (1024 px/block)
__global__ void k_gray_minmax(const float* __restrict__ x,
                              unsigned long long* __restrict__ minmax) {
    const int img   = blockIdx.x >> 8;
    const int chunk = blockIdx.x & 255;
    const long long pix = (long long)img * HW + (long long)chunk * 1024 + threadIdx.x * 4;
    const long long f0  = pix * 3;  // pix % 4 == 0 -> f0 % 12 == 0
    const float4* xv = (const float4*)x;
    const float4 a = xv[f0 / 4 + 0];
    const float4 b = xv[f0 / 4 + 1];
    const float4 c = xv[f0 / 4 + 2];
    const double g0 = gray_of(a.x, a.y, a.z);
    const double g1 = gray_of(a.w, b.x, b.y);
    const double g2 = gray_of(b.z, b.w, c.x);
    const double g3 = gray_of(c.y, c.z, c.w);
    double mn = fmin(fmin(g0, g1), fmin(g2, g3));
    double mx = fmax(fmax(g0, g1), fmax(g2, g3));
    #pragma unroll
    for (int off = 32; off; off >>= 1) {
        mn = fmin(mn, __shfl_xor(mn, off));
        mx = fmax(mx, __shfl_xor(mx, off));
    }
    __shared__ double smn[4], smx[4];
    const int wid = threadIdx.x >> 6;
    if ((threadIdx.x & 63) == 0) { smn[wid] = mn; smx[wid] = mx; }
    __syncthreads();
    if (threadIdx.x == 0) {
        mn = fmin(fmin(smn[0], smn[1]), fmin(smn[2], smn[3]));
        mx = fmax(fmax(smx[0], smx[1]), fmax(smx[2], smx[3]));
        // gray >= 0 always: u64 ordering == double ordering for non-negative values
        atomicMin(&minmax[img * 2 + 0], (unsigned long long)__double_as_longlong(mn));
        atomicMax(&minmax[img * 2 + 1], (unsigned long long)__double_as_longlong(mx));
    }
}

// 32 blocks per image, 256 threads, 32 px/thread (8192 px/block), LDS histogram
__global__ void k_hist(const float* __restrict__ x,
                       const unsigned long long* __restrict__ minmax,
                       unsigned* __restrict__ hist) {
    __shared__ unsigned lh[NBINS];
    for (int i = threadIdx.x; i < NBINS; i += blockDim.x) lh[i] = 0u;
    __syncthreads();
    const int img   = blockIdx.x >> 5;
    const int chunk = blockIdx.x & 31;
    const double mn    = __longlong_as_double((long long)minmax[img * 2 + 0]);
    const double mx    = __longlong_as_double((long long)minmax[img * 2 + 1]);
    const double rng   = fmax(mx - mn, 1e-12);
    const double scale = 256.0 / rng;
    const long long base = (long long)img * HW + (long long)chunk * 8192;
    const float4* xv = (const float4*)x;
    for (int k = 0; k < 8; ++k) {
        const long long p  = base + k * 1024 + threadIdx.x * 4;
        const long long f0 = p * 3;
        const float4 a = xv[f0 / 4 + 0];
        const float4 b = xv[f0 / 4 + 1];
        const float4 c = xv[f0 / 4 + 2];
        double g[4];
        g[0] = gray_of(a.x, a.y, a.z);
        g[1] = gray_of(a.w, b.x, b.y);
        g[2] = gray_of(b.z, b.w, c.x);
        g[3] = gray_of(c.y, c.z, c.w);
        #pragma unroll
        for (int j = 0; j < 4; ++j) {
            int idx = (int)((g[j] - mn) * scale);   // trunc, like astype(int32)
            idx = idx < 0 ? 0 : (idx > 255 ? 255 : idx);
            atomicAdd(&lh[idx], 1u);
        }
    }
    __syncthreads();
    for (int i = threadIdx.x; i < NBINS; i += blockDim.x)
        if (lh[i]) atomicAdd(&hist[img * NBINS + i], lh[i]);
}

// one block per image; thread 0 runs the serial f64 Otsu pipeline
__global__ void k_otsu(const unsigned* __restrict__ hist,
                       const unsigned long long* __restrict__ minmax,
                       double* __restrict__ thr) {
    __shared__ double h[NBINS], w2[NBINS], m2[NBINS];
    const int img = blockIdx.x;
    for (int i = threadIdx.x; i < NBINS; i += blockDim.x)
        h[i] = (double)hist[img * NBINS + i];
    __syncthreads();
    if (threadIdx.x == 0) {
        const double mn   = __longlong_as_double((long long)minmax[img * 2 + 0]);
        const double mx   = __longlong_as_double((long long)minmax[img * 2 + 1]);
        const double rng  = fmax(mx - mn, 1e-12);
        const double step = rng / 256.0;
        // backward pass: w2[i], m2[i]
        double acc = 0.0, acch = 0.0;
        for (int i = NBINS - 1; i >= 0; --i) {
            const double c = mn + ((double)i + 0.5) * step;
            acc  += h[i];
            acch += h[i] * c;
            w2[i] = acc;
            m2[i] = acch / fmax(acc, 1e-12);
        }
        // forward pass fused with between-class variance argmax
        acc = 0.0; acch = 0.0;
        double best = -1.0; int bi = 0;
        for (int t = 0; t < NBINS - 1; ++t) {
            const double c = mn + ((double)t + 0.5) * step;
            acc  += h[t];
            acch += h[t] * c;
            const double m1 = acch / fmax(acc, 1e-12);
            const double d  = m1 - m2[t + 1];
            const double v  = acc * w2[t + 1] * (d * d);
            if (v > best) { best = v; bi = t; }   // strict > == first-occurrence argmax
        }
        thr[img] = mn + ((double)bi + 0.5) * step;
    }
}

// 256 blocks per image, 256 threads, 4 px/thread; write 3 float4 per thread
__global__ void k_binarize(const float* __restrict__ x, const double* __restrict__ thr,
                           float* __restrict__ out) {
    const int img   = blockIdx.x >> 8;
    const int chunk = blockIdx.x & 255;
    const long long pix = (long long)img * HW + (long long)chunk * 1024 + threadIdx.x * 4;
    const long long f0  = pix * 3;
    const float4* xv = (const float4*)x;
    const float4 a = xv[f0 / 4 + 0];
    const float4 b = xv[f0 / 4 + 1];
    const float4 c = xv[f0 / 4 + 2];
    const double t  = thr[img];
    const float b0 = gray_of(a.x, a.y, a.z) > t ? 255.f : 0.f;
    const float b1 = gray_of(a.w, b.x, b.y) > t ? 255.f : 0.f;
    const float b2 = gray_of(b.z, b.w, c.x) > t ? 255.f : 0.f;
    const float b3 = gray_of(c.y, c.z, c.w) > t ? 255.f : 0.f;
    float4* ov = (float4*)out;
    ov[f0 / 4 + 0] = make_float4(b0, b0, b0, b1);
    ov[f0 / 4 + 1] = make_float4(b1, b1, b2, b2);
    ov[f0 / 4 + 2] = make_float4(b2, b3, b3, b3);
}

extern "C" void kernel_launch(void* const* d_in, const int* in_sizes, int n_in,
                              void* d_out, int out_size, void* d_ws, size_t ws_size,
                              hipStream_t stream) {
    const float* x = (const float*)d_in[0];
    float* out = (float*)d_out;
    uint8_t* ws = (uint8_t*)d_ws;

    // ws layout: [0,1024) minmax u64 pairs | [1024,1536) thr f64 | [1536,67072) hist u32
    unsigned long long* minmax = (unsigned long long*)(ws);
    double*             thr    = (double*)(ws + 1024);
    unsigned*           hist   = (unsigned*)(ws + 1536);

    k_init<<<(NIMG * NBINS + NIMG + 255) / 256, 256, 0, stream>>>(minmax, hist);
    k_gray_minmax<<<NIMG * 256, 256, 0, stream>>>(x, minmax);
    k_hist<<<NIMG * 32, 256, 0, stream>>>(x, minmax, hist);
    k_otsu<<<NIMG, 256, 0, stream>>>(hist, minmax, thr);
    k_binarize<<<NIMG * 256, 256, 0, stream>>>(x, thr, out);
}

// Round 4
// 155.222 us; speedup vs baseline: 1.6563x; 1.6563x over previous
//
#include <hip/hip_runtime.h>
#include <stdint.h>

#define NBINS 256
#define HW    (512 * 512)
#define NIMG  64
#define RB 0
#define GB 1032
#define BB 2064
#define STW 3096   // SoA staging words (12.4 KB)

// f64 grayscale, exact same op order as round-3 (verified absmax 0):
__device__ __forceinline__ double gray_of(float r, float g, float b) {
    return fma((double)b, (double)0.1140f,
           fma((double)g, (double)0.5870f,
               (double)r * (double)0.2989f));
}

// Scatter one 1024-px tile (768 float4, fully coalesced loads) into SoA LDS.
__device__ __forceinline__ void stage3(const float4* __restrict__ xv, int64_t tile4,
                                       float* __restrict__ st, int tid) {
    #pragma unroll
    for (int k = 0; k < 3; ++k) {
        const int q = k * 256 + tid;
        const float4 v = xv[tile4 + q];
        const int f0 = q * 4;
        int p = (int)(((unsigned)f0 * 21846u) >> 16);  // f0/3
        int c = f0 - 3 * p;                            // f0%3
        const float e[4] = {v.x, v.y, v.z, v.w};
        #pragma unroll
        for (int j = 0; j < 4; ++j) {
            const int base = (c == 0) ? RB : ((c == 1) ? GB : BB);
            st[base + p] = e[j];
            if (++c == 3) { c = 0; ++p; }
        }
    }
}

__global__ void k_init(unsigned long long* __restrict__ minmax, unsigned* __restrict__ hist) {
    const int i = blockIdx.x * 256 + threadIdx.x;
    if (i < NIMG * NBINS) hist[i] = 0u;
    if (i < NIMG) {
        minmax[i * 2 + 0] = 0x7FF0000000000000ULL;  // +inf
        minmax[i * 2 + 1] = 0ULL;                   // 0.0
    }
}

// 64 blocks/img x 4 tiles: gray + per-image min/max
__global__ __launch_bounds__(256) void k_minmax(const float* __restrict__ x,
                                                unsigned long long* __restrict__ minmax) {
    __shared__ float st[STW];
    __shared__ double smn[4], smx[4];
    const int tid = threadIdx.x;
    const int img = blockIdx.x >> 6;
    const int blk = blockIdx.x & 63;
    const int64_t img4 = (int64_t)img * (HW * 3 / 4);
    const float4* xv = (const float4*)x;
    double mn = 1e300, mx = -1e300;
    for (int it = 0; it < 4; ++it) {
        const int tl = blk * 4 + it;
        __syncthreads();
        stage3(xv, img4 + (int64_t)tl * 768, st, tid);
        __syncthreads();
        const float4 R = *(const float4*)&st[RB + 4 * tid];
        const float4 G = *(const float4*)&st[GB + 4 * tid];
        const float4 B = *(const float4*)&st[BB + 4 * tid];
        const double g0 = gray_of(R.x, G.x, B.x), g1 = gray_of(R.y, G.y, B.y),
                     g2 = gray_of(R.z, G.z, B.z), g3 = gray_of(R.w, G.w, B.w);
        mn = fmin(mn, fmin(fmin(g0, g1), fmin(g2, g3)));
        mx = fmax(mx, fmax(fmax(g0, g1), fmax(g2, g3)));
    }
    #pragma unroll
    for (int off = 32; off; off >>= 1) {
        mn = fmin(mn, __shfl_xor(mn, off));
        mx = fmax(mx, __shfl_xor(mx, off));
    }
    if ((tid & 63) == 0) { smn[tid >> 6] = mn; smx[tid >> 6] = mx; }
    __syncthreads();
    if (tid == 0) {
        mn = fmin(fmin(smn[0], smn[1]), fmin(smn[2], smn[3]));
        mx = fmax(fmax(smx[0], smx[1]), fmax(smx[2], smx[3]));
        atomicMin(&minmax[img * 2 + 0], (unsigned long long)__double_as_longlong(mn));
        atomicMax(&minmax[img * 2 + 1], (unsigned long long)__double_as_longlong(mx));
    }
}

// 32 blocks/img x 8 tiles: histogram (+ optional u8 bin-index emit)
template <bool WIDX>
__global__ __launch_bounds__(256) void k_hist(const float* __restrict__ x,
        const unsigned long long* __restrict__ minmax,
        unsigned* __restrict__ hist, unsigned* __restrict__ idx4) {
    __shared__ float st[STW];
    __shared__ unsigned lh[NBINS];
    const int tid = threadIdx.x;
    const int img = blockIdx.x >> 5;
    const int blk = blockIdx.x & 31;
    lh[tid] = 0u;
    const double mn = __longlong_as_double((long long)minmax[img * 2 + 0]);
    const double mx = __longlong_as_double((long long)minmax[img * 2 + 1]);
    const double scale = 256.0 / fmax(__dsub_rn(mx, mn), 1e-12);
    const int64_t img4 = (int64_t)img * (HW * 3 / 4);
    const float4* xv = (const float4*)x;
    for (int it = 0; it < 8; ++it) {
        const int tl = blk * 8 + it;
        __syncthreads();
        stage3(xv, img4 + (int64_t)tl * 768, st, tid);
        __syncthreads();
        const float4 R = *(const float4*)&st[RB + 4 * tid];
        const float4 G = *(const float4*)&st[GB + 4 * tid];
        const float4 B = *(const float4*)&st[BB + 4 * tid];
        const double g[4] = {gray_of(R.x, G.x, B.x), gray_of(R.y, G.y, B.y),
                             gray_of(R.z, G.z, B.z), gray_of(R.w, G.w, B.w)};
        unsigned pack = 0;
        #pragma unroll
        for (int j = 0; j < 4; ++j) {
            int id = (int)__dmul_rn(__dsub_rn(g[j], mn), scale);  // trunc = astype(int32)
            id = id < 0 ? 0 : (id > 255 ? 255 : id);
            atomicAdd(&lh[id], 1u);
            pack |= (unsigned)id << (8 * j);
        }
        if (WIDX) idx4[img * (HW / 4) + tl * 256 + tid] = pack;
    }
    __syncthreads();
    if (lh[tid]) atomicAdd(&hist[img * NBINS + tid], lh[tid]);
}

// one 256-thread block per image; per-thread ordered partial sums == numpy cumsum bit-exact
__global__ void k_otsu(const unsigned* __restrict__ hist,
                       const unsigned long long* __restrict__ minmax,
                       double* __restrict__ thr, int* __restrict__ bidx) {
    __shared__ double h[NBINS], w2s[NBINS], m2s[NBINS], vv[NBINS];
    const int img = blockIdx.x, t = threadIdx.x;
    h[t] = (double)hist[img * NBINS + t];
    __syncthreads();
    const double mn   = __longlong_as_double((long long)minmax[img * 2 + 0]);
    const double mx   = __longlong_as_double((long long)minmax[img * 2 + 1]);
    const double rng  = fmax(__dsub_rn(mx, mn), 1e-12);
    const double step = rng / 256.0;
    double w1 = 0.0, hc1 = 0.0;
    for (int j = 0; j <= t; ++j) {
        const double c = __dadd_rn(mn, __dmul_rn((double)j + 0.5, step));
        w1  = __dadd_rn(w1, h[j]);
        hc1 = __dadd_rn(hc1, __dmul_rn(h[j], c));
    }
    const double m1 = hc1 / fmax(w1, 1e-12);
    double w2 = 0.0, hc2 = 0.0;
    for (int j = NBINS - 1; j >= t; --j) {
        const double c = __dadd_rn(mn, __dmul_rn((double)j + 0.5, step));
        w2  = __dadd_rn(w2, h[j]);
        hc2 = __dadd_rn(hc2, __dmul_rn(h[j], c));
    }
    w2s[t] = w2;
    m2s[t] = hc2 / fmax(w2, 1e-12);
    __syncthreads();
    if (t < NBINS - 1) {
        const double d = __dsub_rn(m1, m2s[t + 1]);
        vv[t] = __dmul_rn(__dmul_rn(w1, w2s[t + 1]), __dmul_rn(d, d));
    }
    __syncthreads();
    if (t == 0) {
        double best = -1.0; int bi = 0;
        for (int i = 0; i < NBINS - 1; ++i)
            if (vv[i] > best) { best = vv[i]; bi = i; }   // first-occurrence argmax
        thr[img]  = __dadd_rn(mn, __dmul_rn((double)bi + 0.5, step));
        bidx[img] = bi;
    }
}

// 64 blocks/img x 4 tiles: binarize + channel-replicate, fully coalesced output
template <bool UIDX>
__global__ __launch_bounds__(256) void k_binarize(const float* __restrict__ x,
        const unsigned* __restrict__ idx4,
        const double* __restrict__ thr, const int* __restrict__ bidx,
        float* __restrict__ out) {
    __shared__ float st[STW];        // only used when !UIDX
    __shared__ float bst[1024];
    const int tid = threadIdx.x;
    const int img = blockIdx.x >> 6;
    const int blk = blockIdx.x & 63;
    const double T = thr[img];
    const int bi = UIDX ? bidx[img] : 0;
    const int64_t img4 = (int64_t)img * (HW * 3 / 4);
    const float4* xv = (const float4*)x;
    for (int it = 0; it < 4; ++it) {
        const int tl = blk * 4 + it;
        float bb[4];
        if (UIDX) {
            const unsigned pk = idx4[img * (HW / 4) + tl * 256 + tid];
            #pragma unroll
            for (int j = 0; j < 4; ++j) {
                const int id = (pk >> (8 * j)) & 255;
                float r;
                if (id > bi)      r = 255.f;
                else if (id < bi) r = 0.f;
                else {  // rare (~1/256): boundary bin, recompute exact gray
                    const int64_t p = (int64_t)img * HW + (int64_t)tl * 1024 + 4 * tid + j;
                    const double g = gray_of(x[3 * p], x[3 * p + 1], x[3 * p + 2]);
                    r = (g > T) ? 255.f : 0.f;
                }
                bb[j] = r;
            }
            __syncthreads();
        } else {
            __syncthreads();
            stage3(xv, img4 + (int64_t)tl * 768, st, tid);
            __syncthreads();
            const float4 R = *(const float4*)&st[RB + 4 * tid];
            const float4 G = *(const float4*)&st[GB + 4 * tid];
            const float4 B = *(const float4*)&st[BB + 4 * tid];
            bb[0] = (gray_of(R.x, G.x, B.x) > T) ? 255.f : 0.f;
            bb[1] = (gray_of(R.y, G.y, B.y) > T) ? 255.f : 0.f;
            bb[2] = (gray_of(R.z, G.z, B.z) > T) ? 255.f : 0.f;
            bb[3] = (gray_of(R.w, G.w, B.w) > T) ? 255.f : 0.f;
        }
        *(float4*)&bst[4 * tid] = make_float4(bb[0], bb[1], bb[2], bb[3]);
        __syncthreads();
        const int64_t ob4 = img4 + (int64_t)tl * 768;
        #pragma unroll
        for (int k = 0; k < 3; ++k) {
            const int q  = k * 256 + tid;
            const int p0 = (int)(((unsigned)(q * 4) * 21846u) >> 16);  // (4q)/3
            const int m  = q - 3 * (int)(((unsigned)q * 21846u) >> 16); // q%3 == (4q)%3
            const float lo = bst[p0];
            const float hi = bst[p0 + 1 < 1024 ? p0 + 1 : 1023];
            float4 o;
            o.x = lo;
            o.y = (m + 1 >= 3) ? hi : lo;
            o.z = (m + 2 >= 3) ? hi : lo;
            o.w = (m + 3 >= 3) ? hi : lo;
            ((float4*)out)[ob4 + q] = o;
        }
        __syncthreads();   // protect bst before next tile overwrites
    }
}

extern "C" void kernel_launch(void* const* d_in, const int* in_sizes, int n_in,
                              void* d_out, int out_size, void* d_ws, size_t ws_size,
                              hipStream_t stream) {
    const float* x = (const float*)d_in[0];
    float* out = (float*)d_out;
    uint8_t* ws = (uint8_t*)d_ws;

    // ws: [0,1024) minmax u64 | [1024,1536) thr f64 | [1536,1792) bidx i32 |
    //     [2048,67584) hist u32 | [67584, +16MiB) idx u8 (optional)
    unsigned long long* minmax = (unsigned long long*)(ws);
    double*             thr    = (double*)(ws + 1024);
    int*                bidx   = (int*)(ws + 1536);
    unsigned*           hist   = (unsigned*)(ws + 2048);
    unsigned*           idx4   = (unsigned*)(ws + 67584);
    const bool use_idx = ws_size >= (size_t)67584 + (size_t)NIMG * HW;

    k_init<<<64, 256, 0, stream>>>(minmax, hist);
    k_minmax<<<NIMG * 64, 256, 0, stream>>>(x, minmax);
    if (use_idx) k_hist<true ><<<NIMG * 32, 256, 0, stream>>>(x, minmax, hist, idx4);
    else         k_hist<false><<<NIMG * 32, 256, 0, stream>>>(x, minmax, hist, nullptr);
    k_otsu<<<NIMG, 256, 0, stream>>>(hist, minmax, thr, bidx);
    if (use_idx) k_binarize<true ><<<NIMG * 64, 256, 0, stream>>>(x, idx4, thr, bidx, out);
    else         k_binarize<false><<<NIMG * 64, 256, 0, stream>>>(x, nullptr, thr, bidx, out);
}